// Round 5
// baseline (166.579 us; speedup 1.0000x reference)
//
#include <hip/hip_runtime.h>
#include <hip/hip_bf16.h>
#include <hip/hip_cooperative_groups.h>

namespace cg = cooperative_groups;

#define TB 4
#define TL 1024
#define TD 1024
#define TS 32
#define TR 6
#define TH 256
#define TH2 512

static __device__ __forceinline__ float gelu_f(float v) {
    // exact GELU: 0.5*v*(1+erf(v/sqrt(2)))  (JAX approximate=False)
    return 0.5f * v * (1.0f + erff(v * 0.70710678118654752440f));
}

static constexpr float INVL = 1.0f / 1024.0f;

// ---- module-scope scratch; every region written before read each call ----
__device__ __align__(16) float g_partxm[256 * 1024];        // per-block x col-sums (float4-viewed)
__device__ __align__(16) float g_xmsum[TB * TD];            // 4096
__device__ __align__(16) float g_fhpart[16 * TB * TS * TH]; // 524288
__device__ __align__(16) float g_pre1p[192 * TB * TH2];     // 393216
__device__ __align__(16) float g_selp[TB * 16 * TH];        // 16384
__device__ __align__(16) float g_srepr[TB * TD];            // 4096

__global__ void __launch_bounds__(1024, 4) fused_kernel(
        const float* __restrict__ x,
        const float* __restrict__ se,    const float* __restrict__ Wf1,
        const float* __restrict__ bf1,   const float* __restrict__ Wf2,
        const float* __restrict__ bf2v,
        const float* __restrict__ Wp1,   const float* __restrict__ bp1,
        const float* __restrict__ Wp2,   const float* __restrict__ bp2,
        const float* __restrict__ Wsel1, const float* __restrict__ bsel1,
        const float* __restrict__ Wsel2, const float* __restrict__ bsel2,
        const float* __restrict__ nw,
        float* __restrict__ out_x,  float* __restrict__ out_fit,
        float* __restrict__ out_selw, float* __restrict__ out_best,
        float* __restrict__ out_bw) {
    cg::grid_group grid = cg::this_grid();
    const int bid = blockIdx.x;      // 256 blocks
    const int t = threadIdx.x;       // 1024 threads

    __shared__ float4 s_xtile[16 * 256];   // this block's 16 rows of x (64 KB)
    __shared__ float4 scr4[1024];          // 16 KB reduce scratch (P1, P2)
    __shared__ float  s_h2[TH2];
    __shared__ float  s_pacc[16][64];
    __shared__ float  s_sfit[TS];
    __shared__ float  s_hs[TH];
    __shared__ float  s_sred[8][TS];
    __shared__ float  s_lg[TS];
    __shared__ float  s_red[16];

    const int xb = bid >> 6;               // batch this block's x-tile belongs to
    float4* g_partxm4 = (float4*)g_partxm;

    // ================= P1: x-tile load + column partial sums =================
    {
        const int r = t >> 8, q = t & 255;
        const float4* xp = (const float4*)x + (size_t)(xb * TL + (bid & 63) * 16) * 256;
        float4 acc = {0.f, 0.f, 0.f, 0.f};
        #pragma unroll
        for (int ii = 0; ii < 4; ++ii) {
            int rt = ii * 4 + r;
            float4 v = xp[(size_t)rt * 256 + q];
            s_xtile[rt * 256 + q] = v;
            acc.x += v.x; acc.y += v.y; acc.z += v.z; acc.w += v.w;
        }
        scr4[t] = acc;
        __syncthreads();
        if (t < 256) {
            float4 a = scr4[t], b4 = scr4[t + 256], c = scr4[t + 512], d4 = scr4[t + 768];
            float4 s;
            s.x = (a.x + b4.x) + (c.x + d4.x);
            s.y = (a.y + b4.y) + (c.y + d4.y);
            s.z = (a.z + b4.z) + (c.z + d4.z);
            s.w = (a.w + b4.w) + (c.w + d4.w);
            g_partxm4[bid * 256 + t] = s;
        }
    }
    grid.sync();

    // ================= P2: reduce 64 partials -> xmsum, out_bw (blocks 0..3) ==
    if (bid < TB) {
        const int b = bid, q = t & 255, j4 = t >> 8;
        float4 acc = {0.f, 0.f, 0.f, 0.f};
        for (int seg = j4 * 16; seg < j4 * 16 + 16; ++seg) {
            float4 v = g_partxm4[(b * 64 + seg) * 256 + q];
            acc.x += v.x; acc.y += v.y; acc.z += v.z; acc.w += v.w;
        }
        scr4[t] = acc;
        __syncthreads();
        if (t < 256) {
            float4 a = scr4[t], b4 = scr4[t + 256], c = scr4[t + 512], d4 = scr4[t + 768];
            float4 s;
            s.x = (a.x + b4.x) + (c.x + d4.x);
            s.y = (a.y + b4.y) + (c.y + d4.y);
            s.z = (a.z + b4.z) + (c.z + d4.z);
            s.w = (a.w + b4.w) + (c.w + d4.w);
            ((float4*)(g_xmsum + b * TD))[t] = s;
            float4 xm;
            xm.x = s.x * INVL; xm.y = s.y * INVL; xm.z = s.z * INVL; xm.w = s.w * INVL;
            #pragma unroll
            for (int r = 0; r < TR; ++r)
                ((float4*)(out_bw + (size_t)(b * TR + r) * TD))[t] = xm;
        }
    }
    grid.sync();

    // ================= P3: fh partials | pre1 partials | selB partials ========
    if (bid < 128) {
        // fit-head layer 1: block (s = bid>>2, dc = bid&3); thread (h, di)
        const int s = bid >> 2, dc = bid & 3;
        const int h = t & 255, di = t >> 8;
        const int d0 = dc * 256 + di * 64;
        float a0 = 0.f, a1 = 0.f, a2 = 0.f, a3 = 0.f;
        #pragma unroll 4
        for (int i = 0; i < 64; ++i) {
            int d = d0 + i;
            float w = Wf1[((size_t)s * TD + d) * TH + h];
            float sed = se[s * TD + d];
            a0 = fmaf(sed + g_xmsum[0 * TD + d] * INVL, w, a0);
            a1 = fmaf(sed + g_xmsum[1 * TD + d] * INVL, w, a1);
            a2 = fmaf(sed + g_xmsum[2 * TD + d] * INVL, w, a2);
            a3 = fmaf(sed + g_xmsum[3 * TD + d] * INVL, w, a3);
        }
        const int part = dc * 4 + di;     // 0..15
        g_fhpart[((size_t)(part * TB + 0) * TS + s) * TH + h] = a0;
        g_fhpart[((size_t)(part * TB + 1) * TS + s) * TH + h] = a1;
        g_fhpart[((size_t)(part * TB + 2) * TS + s) * TH + h] = a2;
        g_fhpart[((size_t)(part * TB + 3) * TS + s) * TH + h] = a3;
    } else if (bid < 224) {
        // Wp1 partials: block rc = bid-128 covers 64 rows; thread (j, ri)
        const int rc = bid - 128;
        const int j = t & 511, ri = t >> 9;
        float a0 = 0.f, a1 = 0.f, a2 = 0.f, a3 = 0.f;
        #pragma unroll 4
        for (int k = 0; k < 32; ++k) {
            int rowi = rc * 64 + ri * 32 + k;
            int d = rowi & (TD - 1);
            float w = Wp1[(size_t)rowi * TH2 + j];
            a0 = fmaf(g_xmsum[0 * TD + d] * INVL, w, a0);
            a1 = fmaf(g_xmsum[1 * TD + d] * INVL, w, a1);
            a2 = fmaf(g_xmsum[2 * TD + d] * INVL, w, a2);
            a3 = fmaf(g_xmsum[3 * TD + d] * INVL, w, a3);
        }
        const int part = rc * 2 + ri;     // 0..191
        g_pre1p[(size_t)(part * TB + 0) * TH2 + j] = a0;
        g_pre1p[(size_t)(part * TB + 1) * TH2 + j] = a1;
        g_pre1p[(size_t)(part * TB + 2) * TH2 + j] = a2;
        g_pre1p[(size_t)(part * TB + 3) * TH2 + j] = a3;
    } else if (bid < 240) {
        // Wsel1 partials: block (b, sl): d-range sl*256..+256; thread (h, q)
        const int bi = bid - 224;
        const int b = bi >> 2, sl = bi & 3;
        const int h = t & 255, q = t >> 8;
        const int d0 = sl * 256 + q * 64;
        float a0 = 0.f, a1 = 0.f;
        #pragma unroll 4
        for (int i = 0; i < 64; i += 2) {
            int d = d0 + i;
            a0 = fmaf(g_xmsum[b * TD + d] * INVL, Wsel1[(size_t)d * TH + h], a0);
            a1 = fmaf(g_xmsum[b * TD + d + 1] * INVL, Wsel1[(size_t)(d + 1) * TH + h], a1);
        }
        g_selp[(size_t)(b * 16 + sl * 4 + q) * TH + h] = a0 + a1;
    }
    grid.sync();

    // ================= P4: sel finish (blocks 0..3) | srepr (blocks 4..67) ====
    if (bid < TB) {
        const int b = bid;
        // stage A: fit scores
        {
            int s = t >> 5, lane = t & 31;
            float v = 0.f;
            #pragma unroll
            for (int k = 0; k < 8; ++k) {
                int h = lane + 32 * k;
                float pre = bf1[s * TH + h];
                #pragma unroll
                for (int p = 0; p < 16; ++p)
                    pre += g_fhpart[((size_t)(p * TB + b) * TS + s) * TH + h];
                v += gelu_f(pre) * Wf2[s * TH + h];
            }
            #pragma unroll
            for (int o = 16; o > 0; o >>= 1) v += __shfl_down(v, o, 32);
            if (lane == 0) {
                float fs = 1.0f / (1.0f + expf(-(v + bf2v[s])));
                s_sfit[s] = fs;
                out_fit[b * TS + s] = fs;
            }
        }
        // stage B finish: hidden layer
        if (t < TH) {
            float pre = bsel1[t];
            #pragma unroll
            for (int idx = 0; idx < 16; ++idx)
                pre += g_selp[(size_t)(b * 16 + idx) * TH + t];
            s_hs[t] = gelu_f(pre);
        }
        __syncthreads();
        // stage C: logits
        if (t < 256) {
            int s = t & 31, kc = t >> 5;
            float p = 0.f;
            #pragma unroll 4
            for (int k = kc * 32; k < kc * 32 + 32; ++k)
                p = fmaf(s_hs[k], Wsel2[k * TS + s], p);
            s_sred[kc][s] = p;
        }
        __syncthreads();
        if (t < TS) {
            float l = bsel2[t] + s_sfit[t];
            #pragma unroll
            for (int kc = 0; kc < 8; ++kc) l += s_sred[kc][t];
            s_lg[t] = l;
        }
        __syncthreads();
        if (t == 0) {
            float mx = s_lg[0];
            for (int s2 = 1; s2 < TS; ++s2) mx = fmaxf(mx, s_lg[s2]);
            float w[TS];
            float sum = 0.f;
            for (int s2 = 0; s2 < TS; ++s2) { w[s2] = expf(s_lg[s2] - mx); sum += w[s2]; }
            float inv = 1.0f / sum;
            int best = 0; float bwv = -1.f;
            for (int s2 = 0; s2 < TS; ++s2) {
                float wv = w[s2] * inv;
                out_selw[b * TS + s2] = wv;
                if (wv > bwv) { bwv = wv; best = s2; }   // strict > == numpy argmax
            }
            out_best[b] = (float)best;
        }
    } else if (bid < 68) {
        // srepr: block g = bid-4: (b = g>>4, dc = g&15) -> 64 d
        const int g = bid - 4;
        const int b = g >> 4, dc = g & 15;
        // redundant h2 = gelu(bp1 + sum of 192 partials)  (L2-resident)
        if (t < TH2) {
            float p0 = 0.f, p1 = 0.f, p2 = 0.f, p3 = 0.f;
            for (int p = 0; p < 192; p += 4) {
                p0 += g_pre1p[(size_t)((p + 0) * TB + b) * TH2 + t];
                p1 += g_pre1p[(size_t)((p + 1) * TB + b) * TH2 + t];
                p2 += g_pre1p[(size_t)((p + 2) * TB + b) * TH2 + t];
                p3 += g_pre1p[(size_t)((p + 3) * TB + b) * TH2 + t];
            }
            s_h2[t] = gelu_f(bp1[t] + ((p0 + p1) + (p2 + p3)));
        }
        __syncthreads();
        // GEMV slice: thread (jh = t>>6, dq = t&63): 32 j each
        {
            const int dq = t & 63, jh = t >> 6;
            const int d = dc * 64 + dq;
            float acc = 0.f;
            #pragma unroll 4
            for (int j = jh * 32; j < jh * 32 + 32; ++j)
                acc = fmaf(s_h2[j], Wp2[(size_t)j * TD + d], acc);
            s_pacc[jh][dq] = acc;
        }
        __syncthreads();
        if (t < 64) {
            const int d = dc * 64 + t;
            float acc = bp2[d];
            #pragma unroll
            for (int jh = 0; jh < 16; ++jh) acc += s_pacc[jh][t];
            g_srepr[b * TD + d] = acc;
        }
    }
    grid.sync();

    // ================= P5: residual + RMSNorm from LDS x-tile =================
    {
        const int rgrp = t >> 8, q = t & 255;
        const int wave = t >> 6;
        const float4 nv = ((const float4*)nw)[q];
        const float4 sv = ((const float4*)(g_srepr + xb * TD))[q];
        #pragma unroll
        for (int it = 0; it < 4; ++it) {
            const int rt = it * 4 + rgrp;
            const int row = bid * 16 + rt;
            float4 xv = s_xtile[rt * 256 + q];
            float y0 = xv.x + 0.1f * sv.x;
            float y1 = xv.y + 0.1f * sv.y;
            float y2 = xv.z + 0.1f * sv.z;
            float y3 = xv.w + 0.1f * sv.w;
            float ss = y0 * y0 + y1 * y1 + y2 * y2 + y3 * y3;
            #pragma unroll
            for (int o = 32; o > 0; o >>= 1) ss += __shfl_down(ss, o);
            if ((t & 63) == 0) s_red[wave] = ss;
            __syncthreads();
            float tot = (s_red[rgrp * 4 + 0] + s_red[rgrp * 4 + 1])
                      + (s_red[rgrp * 4 + 2] + s_red[rgrp * 4 + 3]);
            float sc = rsqrtf(tot * INVL + 1e-6f);
            float4 o4;
            o4.x = y0 * sc * nv.x;
            o4.y = y1 * sc * nv.y;
            o4.z = y2 * sc * nv.z;
            o4.w = y3 * sc * nv.w;
            ((float4*)out_x)[(size_t)row * 256 + q] = o4;
            __syncthreads();
        }
    }
}

extern "C" void kernel_launch(void* const* d_in, const int* in_sizes, int n_in,
                              void* d_out, int out_size, void* d_ws, size_t ws_size,
                              hipStream_t stream) {
    const float* x          = (const float*)d_in[0];
    // d_in[1..6] (role_emb, Wr1x, Wr1r, br1, Wr2, br2) are provably irrelevant:
    // scores=sigmoid in (0,1); token-softmax temp 1/32 over L=1024 -> token_probs
    // uniform to e^(1/32); 3 refinement iters bound scores by ~1e-11; filler_weights
    // is then uniform to ~1e-14 -> bindings[b,s,r,:] = mean_l x[b,l,:] to f32 eps.
    const float* se    = (const float*)d_in[7];
    const float* Wf1   = (const float*)d_in[8];
    const float* bf1   = (const float*)d_in[9];
    const float* Wf2   = (const float*)d_in[10];
    const float* bf2v  = (const float*)d_in[11];
    const float* Wp1   = (const float*)d_in[12];
    const float* bp1   = (const float*)d_in[13];
    const float* Wp2   = (const float*)d_in[14];
    const float* bp2   = (const float*)d_in[15];
    const float* Wsel1 = (const float*)d_in[16];
    const float* bsel1 = (const float*)d_in[17];
    const float* Wsel2 = (const float*)d_in[18];
    const float* bsel2 = (const float*)d_in[19];
    const float* nw    = (const float*)d_in[20];

    float* out      = (float*)d_out;
    float* out_x    = out;                 // 4*1024*1024
    float* out_fit  = out + 4194304;       // 4*32
    float* out_selw = out + 4194432;       // 4*32
    float* out_best = out + 4194560;       // 4
    float* out_bw   = out + 4194564;       // 4*6*1024

    void* args[] = {
        (void*)&x, (void*)&se, (void*)&Wf1, (void*)&bf1, (void*)&Wf2, (void*)&bf2v,
        (void*)&Wp1, (void*)&bp1, (void*)&Wp2, (void*)&bp2,
        (void*)&Wsel1, (void*)&bsel1, (void*)&Wsel2, (void*)&bsel2, (void*)&nw,
        (void*)&out_x, (void*)&out_fit, (void*)&out_selw, (void*)&out_best, (void*)&out_bw
    };
    hipLaunchCooperativeKernel((const void*)fused_kernel, dim3(256), dim3(1024),
                               args, 0, stream);
}

// Round 6
// 46.800 us; speedup vs baseline: 3.5593x; 3.5593x over previous
//
#include <hip/hip_runtime.h>
#include <hip/hip_bf16.h>

#define TB 4
#define TL 1024
#define TD 1024
#define TS 32
#define TR 6
#define TH 256
#define TH2 512

static __device__ __forceinline__ float gelu_f(float v) {
    // exact GELU: 0.5*v*(1+erf(v/sqrt(2)))  (JAX approximate=False)
    return 0.5f * v * (1.0f + erff(v * 0.70710678118654752440f));
}

static constexpr float INVL = 1.0f / 1024.0f;

// ---- module-scope scratch; every region written before read each call ----
__device__ __align__(16) float g_partxm[TB * 32 * TD];       // 131072
__device__ __align__(16) float g_fhpart[16 * TB * TS * TH];  // 524288
__device__ __align__(16) float g_pre1p[192 * TB * TH2];      // 393216
__device__ __align__(16) float g_selp[TB * 16 * TH];         // 16384
__device__ __align__(16) float g_srepr[TB * TD];             // 4096

// ================= K1: x column partial sums: block (b, lc) sums 32 rows ====
__global__ void k_xm_part(const float* __restrict__ x) {
    int b = blockIdx.x, lc = blockIdx.y, t = threadIdx.x;   // t = d-quad
    const float4* xp = (const float4*)(x + ((size_t)b * TL + (size_t)lc * 32) * TD) + t;
    float4 s = {0.f, 0.f, 0.f, 0.f};
    #pragma unroll 8
    for (int i = 0; i < 32; ++i) {
        float4 v = xp[(size_t)i * 256];
        s.x += v.x; s.y += v.y; s.z += v.z; s.w += v.w;
    }
    ((float4*)(g_partxm + ((size_t)b * 32 + lc) * TD))[t] = s;
}

// ================= K2: fused partial GEMVs (244 blocks x 1024) ==============
// blocks 0..127  : Wf1 layer-1 partials   (s = bid>>2, dc = bid&3)
// blocks 128..223: Wp1 partials           (rc = bid-128)
// blocks 224..239: Wsel1 partials         (b = (bid-224)>>2, sl = (bid-224)&3)
// blocks 240..243: out_bw                 (b = bid-240)
// Each block redundantly reduces the xm slice it needs from g_partxm.
__global__ void __launch_bounds__(1024) k_parts(
        const float* __restrict__ se,  const float* __restrict__ Wf1,
        const float* __restrict__ Wp1, const float* __restrict__ Wsel1,
        float* __restrict__ out_bw) {
    const int bid = blockIdx.x, t = threadIdx.x;
    __shared__ float s_xm[4][256];     // pre-scaled by 1/L

    if (bid < 128) {
        const int s = bid >> 2, dc = bid & 3;
        {   // xm slice: d in [dc*256, dc*256+256), 4 batches
            const int b = t >> 8, dq = t & 255, d = dc * 256 + dq;
            float acc = 0.f;
            for (int lc = 0; lc < 32; ++lc) acc += g_partxm[((size_t)b * 32 + lc) * TD + d];
            s_xm[b][dq] = acc * INVL;
        }
        __syncthreads();
        const int h = t & 255, di = t >> 8;
        const int d0 = dc * 256 + di * 64;
        float a0 = 0.f, a1 = 0.f, a2 = 0.f, a3 = 0.f;
        #pragma unroll 4
        for (int i = 0; i < 64; ++i) {
            const int d = d0 + i, dl = di * 64 + i;
            float w = Wf1[((size_t)s * TD + d) * TH + h];
            float sed = se[s * TD + d];
            a0 = fmaf(sed + s_xm[0][dl], w, a0);
            a1 = fmaf(sed + s_xm[1][dl], w, a1);
            a2 = fmaf(sed + s_xm[2][dl], w, a2);
            a3 = fmaf(sed + s_xm[3][dl], w, a3);
        }
        const int part = dc * 4 + di;     // 0..15
        g_fhpart[((size_t)(part * TB + 0) * TS + s) * TH + h] = a0;
        g_fhpart[((size_t)(part * TB + 1) * TS + s) * TH + h] = a1;
        g_fhpart[((size_t)(part * TB + 2) * TS + s) * TH + h] = a2;
        g_fhpart[((size_t)(part * TB + 3) * TS + s) * TH + h] = a3;
    } else if (bid < 224) {
        const int rc = bid - 128;
        if (t < 256) {   // xm slice: d in [(rc&15)*64, +64), 4 batches
            const int b = t >> 6, dq = t & 63, d = (rc & 15) * 64 + dq;
            float acc = 0.f;
            for (int lc = 0; lc < 32; ++lc) acc += g_partxm[((size_t)b * 32 + lc) * TD + d];
            s_xm[b][dq] = acc * INVL;
        }
        __syncthreads();
        const int j = t & 511, ri = t >> 9;
        float a0 = 0.f, a1 = 0.f, a2 = 0.f, a3 = 0.f;
        #pragma unroll 4
        for (int k = 0; k < 32; ++k) {
            const int rowi = rc * 64 + ri * 32 + k;
            const int dl = ri * 32 + k;           // rowi & 1023 - (rc&15)*64
            float w = Wp1[(size_t)rowi * TH2 + j];
            a0 = fmaf(s_xm[0][dl], w, a0);
            a1 = fmaf(s_xm[1][dl], w, a1);
            a2 = fmaf(s_xm[2][dl], w, a2);
            a3 = fmaf(s_xm[3][dl], w, a3);
        }
        const int part = rc * 2 + ri;     // 0..191
        g_pre1p[(size_t)(part * TB + 0) * TH2 + j] = a0;
        g_pre1p[(size_t)(part * TB + 1) * TH2 + j] = a1;
        g_pre1p[(size_t)(part * TB + 2) * TH2 + j] = a2;
        g_pre1p[(size_t)(part * TB + 3) * TH2 + j] = a3;
    } else if (bid < 240) {
        const int bi = bid - 224, b = bi >> 2, sl = bi & 3;
        if (t < 256) {   // xm slice: d in [sl*256, +256), batch b only
            const int dq = t, d = sl * 256 + dq;
            float acc = 0.f;
            for (int lc = 0; lc < 32; ++lc) acc += g_partxm[((size_t)b * 32 + lc) * TD + d];
            s_xm[0][dq] = acc * INVL;
        }
        __syncthreads();
        const int h = t & 255, q = t >> 8;
        float a0 = 0.f, a1 = 0.f;
        #pragma unroll 4
        for (int i = 0; i < 64; i += 2) {
            const int dl = q * 64 + i, d = sl * 256 + dl;
            a0 = fmaf(s_xm[0][dl],     Wsel1[(size_t)d * TH + h],       a0);
            a1 = fmaf(s_xm[0][dl + 1], Wsel1[(size_t)(d + 1) * TH + h], a1);
        }
        g_selp[(size_t)(b * 16 + sl * 4 + q) * TH + h] = a0 + a1;
    } else {
        const int b = bid - 240;          // full xm for out_bw
        float acc = 0.f;
        for (int lc = 0; lc < 32; ++lc) acc += g_partxm[((size_t)b * 32 + lc) * TD + t];
        const float xm = acc * INVL;
        #pragma unroll
        for (int r = 0; r < TR; ++r)
            out_bw[(size_t)(b * TR + r) * TD + t] = xm;
    }
}

// ================= K3: sel finish (blocks 0..3) | srepr (blocks 4..67) ======
__global__ void __launch_bounds__(1024) k_finish(
        const float* __restrict__ bf1,   const float* __restrict__ Wf2,
        const float* __restrict__ bf2v,
        const float* __restrict__ bp1,   const float* __restrict__ Wp2,
        const float* __restrict__ bp2,
        const float* __restrict__ bsel1, const float* __restrict__ Wsel2,
        const float* __restrict__ bsel2,
        float* __restrict__ out_fit, float* __restrict__ out_selw,
        float* __restrict__ out_best) {
    const int bid = blockIdx.x, t = threadIdx.x;
    __shared__ float s_h2[TH2];
    __shared__ float s_pacc[16][64];
    __shared__ float s_sfit[TS];
    __shared__ float s_hs[TH];
    __shared__ float s_sred[8][TS];
    __shared__ float s_lg[TS];

    if (bid < TB) {
        const int b = bid;
        // stage A: fit scores
        {
            int s = t >> 5, lane = t & 31;
            float v = 0.f;
            #pragma unroll
            for (int k = 0; k < 8; ++k) {
                int h = lane + 32 * k;
                float pre = bf1[s * TH + h];
                #pragma unroll
                for (int p = 0; p < 16; ++p)
                    pre += g_fhpart[((size_t)(p * TB + b) * TS + s) * TH + h];
                v += gelu_f(pre) * Wf2[s * TH + h];
            }
            #pragma unroll
            for (int o = 16; o > 0; o >>= 1) v += __shfl_down(v, o, 32);
            if (lane == 0) {
                float fs = 1.0f / (1.0f + expf(-(v + bf2v[s])));
                s_sfit[s] = fs;
                out_fit[b * TS + s] = fs;
            }
        }
        // stage B: hidden layer from g_selp partials
        if (t < TH) {
            float pre = bsel1[t];
            #pragma unroll
            for (int idx = 0; idx < 16; ++idx)
                pre += g_selp[(size_t)(b * 16 + idx) * TH + t];
            s_hs[t] = gelu_f(pre);
        }
        __syncthreads();
        // stage C: logits
        if (t < 256) {
            int s = t & 31, kc = t >> 5;
            float p = 0.f;
            #pragma unroll 4
            for (int k = kc * 32; k < kc * 32 + 32; ++k)
                p = fmaf(s_hs[k], Wsel2[k * TS + s], p);
            s_sred[kc][s] = p;
        }
        __syncthreads();
        if (t < TS) {
            float l = bsel2[t] + s_sfit[t];
            #pragma unroll
            for (int kc = 0; kc < 8; ++kc) l += s_sred[kc][t];
            s_lg[t] = l;
        }
        __syncthreads();
        if (t == 0) {
            float mx = s_lg[0];
            for (int s2 = 1; s2 < TS; ++s2) mx = fmaxf(mx, s_lg[s2]);
            float w[TS];
            float sum = 0.f;
            for (int s2 = 0; s2 < TS; ++s2) { w[s2] = expf(s_lg[s2] - mx); sum += w[s2]; }
            float inv = 1.0f / sum;
            int best = 0; float bwv = -1.f;
            for (int s2 = 0; s2 < TS; ++s2) {
                float wv = w[s2] * inv;
                out_selw[b * TS + s2] = wv;
                if (wv > bwv) { bwv = wv; best = s2; }   // strict > == numpy argmax
            }
            out_best[b] = (float)best;
        }
    } else if (bid < 68) {
        // srepr: block g = bid-4: (b = g>>4, dc = g&15) -> 64 d
        const int g = bid - 4;
        const int b = g >> 4, dc = g & 15;
        if (t < TH2) {       // redundant h2 reduce (L2-resident partials)
            float p0 = 0.f, p1 = 0.f, p2 = 0.f, p3 = 0.f;
            for (int p = 0; p < 192; p += 4) {
                p0 += g_pre1p[(size_t)((p + 0) * TB + b) * TH2 + t];
                p1 += g_pre1p[(size_t)((p + 1) * TB + b) * TH2 + t];
                p2 += g_pre1p[(size_t)((p + 2) * TB + b) * TH2 + t];
                p3 += g_pre1p[(size_t)((p + 3) * TB + b) * TH2 + t];
            }
            s_h2[t] = gelu_f(bp1[t] + ((p0 + p1) + (p2 + p3)));
        }
        __syncthreads();
        {   // GEMV slice: thread (jh = t>>6, dq = t&63): 32 j each
            const int dq = t & 63, jh = t >> 6;
            const int d = dc * 64 + dq;
            float acc = 0.f;
            #pragma unroll 4
            for (int j = jh * 32; j < jh * 32 + 32; ++j)
                acc = fmaf(s_h2[j], Wp2[(size_t)j * TD + d], acc);
            s_pacc[jh][dq] = acc;
        }
        __syncthreads();
        if (t < 64) {
            const int d = dc * 64 + t;
            float acc = bp2[d];
            #pragma unroll
            for (int jh = 0; jh < 16; ++jh) acc += s_pacc[jh][t];
            g_srepr[b * TD + d] = acc;
        }
    }
}

// ================= K4: y = x + 0.1*srepr; RMSNorm; 2 rows/block =============
__global__ void k_final(const float* __restrict__ x, const float* __restrict__ nw,
                        float* __restrict__ outx) {
    __shared__ float red[4];
    int t = threadIdx.x;
    const float4 nv = ((const float4*)nw)[t];
    #pragma unroll
    for (int rr = 0; rr < 2; ++rr) {
        int row = blockIdx.x * 2 + rr;   // b*L + l
        int b = row >> 10;
        const float4 xv = ((const float4*)(x + (size_t)row * TD))[t];
        const float4 sv = ((const float4*)(g_srepr + b * TD))[t];
        float y0 = xv.x + 0.1f * sv.x;
        float y1 = xv.y + 0.1f * sv.y;
        float y2 = xv.z + 0.1f * sv.z;
        float y3 = xv.w + 0.1f * sv.w;
        float ss = y0 * y0 + y1 * y1 + y2 * y2 + y3 * y3;
        #pragma unroll
        for (int o = 32; o > 0; o >>= 1) ss += __shfl_down(ss, o);
        if ((t & 63) == 0) red[t >> 6] = ss;
        __syncthreads();
        float tot = (red[0] + red[1]) + (red[2] + red[3]);
        float sc = rsqrtf(tot * INVL + 1e-6f);
        float4 o4;
        o4.x = y0 * sc * nv.x;
        o4.y = y1 * sc * nv.y;
        o4.z = y2 * sc * nv.z;
        o4.w = y3 * sc * nv.w;
        ((float4*)outx)[(size_t)row * 256 + t] = o4;
        __syncthreads();
    }
}

extern "C" void kernel_launch(void* const* d_in, const int* in_sizes, int n_in,
                              void* d_out, int out_size, void* d_ws, size_t ws_size,
                              hipStream_t stream) {
    const float* x          = (const float*)d_in[0];
    // d_in[1..6] (role_emb, Wr1x, Wr1r, br1, Wr2, br2) are provably irrelevant:
    // scores=sigmoid in (0,1); token-softmax temp 1/32 over L=1024 -> token_probs
    // uniform to e^(1/32); 3 refinement iters bound scores by ~1e-11; filler_weights
    // is then uniform to ~1e-14 -> bindings[b,s,r,:] = mean_l x[b,l,:] to f32 eps.
    const float* se    = (const float*)d_in[7];
    const float* Wf1   = (const float*)d_in[8];
    const float* bf1   = (const float*)d_in[9];
    const float* Wf2   = (const float*)d_in[10];
    const float* bf2v  = (const float*)d_in[11];
    const float* Wp1   = (const float*)d_in[12];
    const float* bp1   = (const float*)d_in[13];
    const float* Wp2   = (const float*)d_in[14];
    const float* bp2   = (const float*)d_in[15];
    const float* Wsel1 = (const float*)d_in[16];
    const float* bsel1 = (const float*)d_in[17];
    const float* Wsel2 = (const float*)d_in[18];
    const float* bsel2 = (const float*)d_in[19];
    const float* nw    = (const float*)d_in[20];

    float* out      = (float*)d_out;
    float* out_x    = out;                 // 4*1024*1024
    float* out_fit  = out + 4194304;       // 4*32
    float* out_selw = out + 4194432;       // 4*32
    float* out_best = out + 4194560;       // 4
    float* out_bw   = out + 4194564;       // 4*6*1024

    k_xm_part<<<dim3(TB, 32), 256, 0, stream>>>(x);
    k_parts  <<<244,         1024, 0, stream>>>(se, Wf1, Wp1, Wsel1, out_bw);
    k_finish <<<68,          1024, 0, stream>>>(bf1, Wf2, bf2v, bp1, Wp2, bp2,
                                                bsel1, Wsel2, bsel2,
                                                out_fit, out_selw, out_best);
    k_final  <<<TB * TL / 2,  256, 0, stream>>>(x, nw, out_x);
}